// Round 1
// baseline (4404.319 us; speedup 1.0000x reference)
//
#include <hip/hip_runtime.h>
#include <math.h>

#define Nn   100000
#define Ee   3200000
#define NNZn 6400000
#define NF   (Nn * 16)   // floats per node-feature buffer

// ---------------------------------------------------------------------------
// hop: zout[d] += zin[s] for each edge (s,d).  Thread per (edge, float4 chunk).
// ---------------------------------------------------------------------------
__global__ __launch_bounds__(256) void hop_kernel(
    const float* __restrict__ zin, float* __restrict__ zout,
    const int* __restrict__ src, const int* __restrict__ dst) {
  int idx = blockIdx.x * 256 + threadIdx.x;          // over Ee*4
  if (idx >= Ee * 4) return;
  int e = idx >> 2, c = (idx & 3) * 4;
  int s = src[e], d = dst[e];
  float4 v = *(const float4*)(zin + (size_t)s * 16 + c);
  float* p = zout + (size_t)d * 16 + c;
  atomicAdd(p + 0, v.x);
  atomicAdd(p + 1, v.y);
  atomicAdd(p + 2, v.z);
  atomicAdd(p + 3, v.w);
}

// ---------------------------------------------------------------------------
// pm_y[r] += pm_vals[j] * feat_b[pm_cols[j]].  Thread per (nnz, float4 chunk).
// ---------------------------------------------------------------------------
__global__ __launch_bounds__(256) void pm_kernel(
    const float* __restrict__ feat_b, const float* __restrict__ pm_vals,
    const int* __restrict__ pm_rows, const int* __restrict__ pm_cols,
    float* __restrict__ pm_y) {
  int idx = blockIdx.x * 256 + threadIdx.x;          // over NNZn*4
  if (idx >= NNZn * 4) return;
  int j = idx >> 2, c = (idx & 3) * 4;
  int r = pm_rows[j], col = pm_cols[j];
  float v = pm_vals[j];
  float4 f = *(const float4*)(feat_b + (size_t)col * 16 + c);
  float* p = pm_y + (size_t)r * 16 + c;
  atomicAdd(p + 0, v * f.x);
  atomicAdd(p + 1, v * f.y);
  atomicAdd(p + 2, v * f.z);
  atomicAdd(p + 3, v * f.w);
}

// ---------------------------------------------------------------------------
// Fused per-node projections + ReLU(second half) + BN-stat partial reduction.
// Writes pre-BN result to `result` (== d_out), stats sums to stats[0:32].
// ---------------------------------------------------------------------------
__global__ __launch_bounds__(256) void fuse_kernel(
    const float* __restrict__ feat_a, const float* __restrict__ deg,
    const float* __restrict__ z1, const float* __restrict__ z2,
    const float* __restrict__ z4, const float* __restrict__ pmy,
    const float* __restrict__ Wprev, const float* __restrict__ bprev,
    const float* __restrict__ Wdeg,  const float* __restrict__ bdeg,
    const float* __restrict__ Wrad,  const float* __restrict__ brad,
    const float* __restrict__ Wfuse, const float* __restrict__ bfuse,
    float* __restrict__ result, float* __restrict__ stats) {
  __shared__ float sWp[256], sWd[256], sWr[768], sWf[256], sB[16];
  int t = threadIdx.x;
  sWp[t] = Wprev[t];
  sWd[t] = Wdeg[t];
  sWf[t] = Wfuse[t];
  for (int i = t; i < 768; i += 256) sWr[i] = Wrad[i];
  if (t < 16)
    sB[t] = bprev[t] + bdeg[t] + brad[t] + brad[16 + t] + brad[32 + t] + bfuse[t];
  __syncthreads();

  int n = blockIdx.x * 256 + t;
  bool valid = n < Nn;

  float fa[16], a1[16], a2[16], a4[16], py[16];
  float dg = 0.f;
  if (valid) {
    const float4* p;
    p = (const float4*)(feat_a + (size_t)n * 16);
    ((float4*)fa)[0] = p[0]; ((float4*)fa)[1] = p[1];
    ((float4*)fa)[2] = p[2]; ((float4*)fa)[3] = p[3];
    p = (const float4*)(z1 + (size_t)n * 16);
    ((float4*)a1)[0] = p[0]; ((float4*)a1)[1] = p[1];
    ((float4*)a1)[2] = p[2]; ((float4*)a1)[3] = p[3];
    p = (const float4*)(z2 + (size_t)n * 16);
    ((float4*)a2)[0] = p[0]; ((float4*)a2)[1] = p[1];
    ((float4*)a2)[2] = p[2]; ((float4*)a2)[3] = p[3];
    p = (const float4*)(z4 + (size_t)n * 16);
    ((float4*)a4)[0] = p[0]; ((float4*)a4)[1] = p[1];
    ((float4*)a4)[2] = p[2]; ((float4*)a4)[3] = p[3];
    p = (const float4*)(pmy + (size_t)n * 16);
    ((float4*)py)[0] = p[0]; ((float4*)py)[1] = p[1];
    ((float4*)py)[2] = p[2]; ((float4*)py)[3] = p[3];
    dg = deg[n];
  } else {
#pragma unroll
    for (int i = 0; i < 16; i++) { fa[i] = a1[i] = a2[i] = a4[i] = py[i] = 0.f; }
  }

  float out[16];
#pragma unroll
  for (int o = 0; o < 16; o++) {
    float a = sB[o];
#pragma unroll
    for (int i = 0; i < 16; i++) {
      a += fa[i] * (sWp[i * 16 + o] + dg * sWd[i * 16 + o]);
      a += a1[i] * sWr[i * 16 + o];
      a += a2[i] * sWr[256 + i * 16 + o];
      a += a4[i] * sWr[512 + i * 16 + o];
      a += py[i] * sWf[i * 16 + o];
    }
    out[o] = (o >= 8) ? fmaxf(a, 0.f) : a;
  }

  if (valid) {
    float4* r = (float4*)(result + (size_t)n * 16);
    r[0] = ((float4*)out)[0]; r[1] = ((float4*)out)[1];
    r[2] = ((float4*)out)[2]; r[3] = ((float4*)out)[3];
  } else {
#pragma unroll
    for (int o = 0; o < 16; o++) out[o] = 0.f;
  }

  // per-wave reduction of sum / sum-of-squares, one atomic pair per column/wave
#pragma unroll
  for (int o = 0; o < 16; o++) {
    float s = out[o];
    float q = out[o] * out[o];
#pragma unroll
    for (int m = 32; m >= 1; m >>= 1) {
      s += __shfl_xor(s, m, 64);
      q += __shfl_xor(q, m, 64);
    }
    if ((t & 63) == 0) {
      atomicAdd(&stats[o], s);
      atomicAdd(&stats[16 + o], q);
    }
  }
}

// ---------------------------------------------------------------------------
// BN coefficients: stats[32+o]=scale, stats[48+o]=shift
// ---------------------------------------------------------------------------
__global__ void bn_coeffs(float* __restrict__ stats,
                          const float* __restrict__ gamma,
                          const float* __restrict__ beta) {
  int t = threadIdx.x;
  if (t < 16) {
    float mean = stats[t] * (1.0f / Nn);
    float var  = stats[16 + t] * (1.0f / Nn) - mean * mean;
    float sc   = gamma[t] * rsqrtf(var + 1e-5f);
    stats[32 + t] = sc;
    stats[48 + t] = beta[t] - mean * sc;
  }
}

// ---------------------------------------------------------------------------
// BN apply, in place on d_out.  Thread per float4 (column group c*4..c*4+3).
// ---------------------------------------------------------------------------
__global__ __launch_bounds__(256) void bn_apply(
    float* __restrict__ result, const float* __restrict__ stats) {
  int idx = blockIdx.x * 256 + threadIdx.x;          // over Nn*4
  if (idx >= Nn * 4) return;
  int c = (idx & 3) * 4;
  float4 r = ((const float4*)result)[idx];
  float4 o;
  o.x = r.x * stats[32 + c + 0] + stats[48 + c + 0];
  o.y = r.y * stats[32 + c + 1] + stats[48 + c + 1];
  o.z = r.z * stats[32 + c + 2] + stats[48 + c + 2];
  o.w = r.w * stats[32 + c + 3] + stats[48 + c + 3];
  ((float4*)result)[idx] = o;
}

// ---------------------------------------------------------------------------
extern "C" void kernel_launch(void* const* d_in, const int* in_sizes, int n_in,
                              void* d_out, int out_size, void* d_ws, size_t ws_size,
                              hipStream_t stream) {
  const float* feat_a  = (const float*)d_in[0];
  const float* feat_b  = (const float*)d_in[1];
  const float* deg     = (const float*)d_in[2];
  const float* pm_vals = (const float*)d_in[3];
  const float* W_prev  = (const float*)d_in[4];
  const float* b_prev  = (const float*)d_in[5];
  const float* W_deg   = (const float*)d_in[6];
  const float* b_deg   = (const float*)d_in[7];
  const float* W_rad   = (const float*)d_in[8];
  const float* b_rad   = (const float*)d_in[9];
  const float* W_fuse  = (const float*)d_in[10];
  const float* b_fuse  = (const float*)d_in[11];
  const float* bn_g    = (const float*)d_in[12];
  const float* bn_b    = (const float*)d_in[13];
  const int*   src     = (const int*)d_in[14];
  const int*   dst     = (const int*)d_in[15];
  const int*   pm_rows = (const int*)d_in[16];
  const int*   pm_cols = (const int*)d_in[17];
  // d_in[18] = radius (fixed 3 -> hop pattern 1,2,4 hard-coded)

  float* ws    = (float*)d_ws;
  float* z1    = ws;
  float* z2    = ws + (size_t)NF;
  float* z3    = ws + (size_t)2 * NF;
  float* z4    = ws + (size_t)3 * NF;
  float* pm_y  = ws + (size_t)4 * NF;
  float* stats = ws + (size_t)5 * NF;           // 64 floats
  float* result = (float*)d_out;                // pre-BN result lives in d_out

  // zero z1..z4, pm_y, stats
  hipMemsetAsync(d_ws, 0, ((size_t)5 * NF + 64) * sizeof(float), stream);

  int hop_blocks = (Ee * 4 + 255) / 256;        // 50000
  hop_kernel<<<hop_blocks, 256, 0, stream>>>(feat_a, z1, src, dst);
  hop_kernel<<<hop_blocks, 256, 0, stream>>>(z1, z2, src, dst);
  hop_kernel<<<hop_blocks, 256, 0, stream>>>(z2, z3, src, dst);
  hop_kernel<<<hop_blocks, 256, 0, stream>>>(z3, z4, src, dst);

  int pm_blocks = (NNZn * 4 + 255) / 256;       // 100000
  pm_kernel<<<pm_blocks, 256, 0, stream>>>(feat_b, pm_vals, pm_rows, pm_cols, pm_y);

  int fuse_blocks = (Nn + 255) / 256;           // 391
  fuse_kernel<<<fuse_blocks, 256, 0, stream>>>(
      feat_a, deg, z1, z2, z4, pm_y,
      W_prev, b_prev, W_deg, b_deg, W_rad, b_rad, W_fuse, b_fuse,
      result, stats);

  bn_coeffs<<<1, 64, 0, stream>>>(stats, bn_g, bn_b);

  int bn_blocks = (Nn * 4 + 255) / 256;         // 1563
  bn_apply<<<bn_blocks, 256, 0, stream>>>(result, stats);
}

// Round 2
// 2690.538 us; speedup vs baseline: 1.6370x; 1.6370x over previous
//
#include <hip/hip_runtime.h>
#include <math.h>

#define Nn   100000
#define Ee   3200000
#define NNZn 6400000
#define NF   (Nn * 16)   // floats per node-feature buffer

// ---------------------------------------------------------------------------
// Histogram: counts_e[dst[e]]++, counts_p[pm_rows[j]]++  (int atomics, TCC-rate)
// ---------------------------------------------------------------------------
__global__ __launch_bounds__(256) void hist_kernel(
    const int* __restrict__ dst, const int* __restrict__ pm_rows,
    int* __restrict__ counts_e, int* __restrict__ counts_p) {
  int idx = blockIdx.x * 256 + threadIdx.x;
  if (idx < Ee) {
    atomicAdd(&counts_e[dst[idx]], 1);
  } else {
    int j = idx - Ee;
    if (j < NNZn) atomicAdd(&counts_p[pm_rows[j]], 1);
  }
}

// ---------------------------------------------------------------------------
// Exclusive scan of counts (Nn entries) -> row_start[Nn+1] and cursor copy.
// One block of 1024 threads per array; block 0 = edges, block 1 = pm.
// ---------------------------------------------------------------------------
__global__ __launch_bounds__(1024) void scan2_kernel(
    const int* __restrict__ counts_e, const int* __restrict__ counts_p,
    int* __restrict__ rs_e, int* __restrict__ cur_e,
    int* __restrict__ rs_p, int* __restrict__ cur_p) {
  const int* counts = (blockIdx.x == 0) ? counts_e : counts_p;
  int* rs  = (blockIdx.x == 0) ? rs_e  : rs_p;
  int* cur = (blockIdx.x == 0) ? cur_e : cur_p;

  __shared__ int s[1024];
  int t = threadIdx.x;
  const int chunk = (Nn + 1023) / 1024;     // 98
  int lo = t * chunk;
  int hi = min(lo + chunk, Nn);

  int sum = 0;
  for (int i = lo; i < hi; i++) sum += counts[i];
  s[t] = sum;
  __syncthreads();
  // Hillis-Steele inclusive scan
  for (int off = 1; off < 1024; off <<= 1) {
    int v = (t >= off) ? s[t - off] : 0;
    __syncthreads();
    s[t] += v;
    __syncthreads();
  }
  int run = (t == 0) ? 0 : s[t - 1];        // exclusive prefix of this chunk
  for (int i = lo; i < hi; i++) {
    rs[i] = run;
    cur[i] = run;
    run += counts[i];
  }
  if (t == 1023) { rs[Nn] = s[1023]; cur[Nn] = s[1023]; }
}

// ---------------------------------------------------------------------------
// Scatter ids into CSR order. perm_src[pos] = src[e]; perm_pm[pos] = j.
// ---------------------------------------------------------------------------
__global__ __launch_bounds__(256) void scatter_kernel(
    const int* __restrict__ src, const int* __restrict__ dst,
    const int* __restrict__ pm_rows,
    int* __restrict__ cur_e, int* __restrict__ cur_p,
    int* __restrict__ perm_src, int* __restrict__ perm_pm) {
  int idx = blockIdx.x * 256 + threadIdx.x;
  if (idx < Ee) {
    int d = dst[idx];
    int pos = atomicAdd(&cur_e[d], 1);
    perm_src[pos] = src[idx];
  } else {
    int j = idx - Ee;
    if (j < NNZn) {
      int r = pm_rows[j];
      int pos = atomicAdd(&cur_p[r], 1);
      perm_pm[pos] = j;
    }
  }
}

// ---------------------------------------------------------------------------
// Gather hop: zout[n][f] = sum over in-edges of zin[src][f].
// 16 lanes per node (one per feature); 16 nodes per 256-thread block.
// ---------------------------------------------------------------------------
__global__ __launch_bounds__(256) void hop_gather(
    const float* __restrict__ zin, float* __restrict__ zout,
    const int* __restrict__ perm_src, const int* __restrict__ row_start) {
  int t = threadIdx.x;
  int node = blockIdx.x * 16 + (t >> 4);
  int f = t & 15;
  if (node >= Nn) return;
  int b = row_start[node], e2 = row_start[node + 1];
  float acc0 = 0.f, acc1 = 0.f;
  int i = b;
  for (; i + 2 <= e2; i += 2) {
    int s0 = perm_src[i];
    int s1 = perm_src[i + 1];
    acc0 += zin[(size_t)s0 * 16 + f];
    acc1 += zin[(size_t)s1 * 16 + f];
  }
  if (i < e2) acc0 += zin[(size_t)perm_src[i] * 16 + f];
  zout[(size_t)node * 16 + f] = acc0 + acc1;
}

// ---------------------------------------------------------------------------
// Gather pm: pm_y[r][f] = sum_j pm_vals[j] * feat_b[pm_cols[j]][f]
// ---------------------------------------------------------------------------
__global__ __launch_bounds__(256) void pm_gather(
    const float* __restrict__ feat_b, const float* __restrict__ pm_vals,
    const int* __restrict__ pm_cols,
    const int* __restrict__ perm_pm, const int* __restrict__ row_start,
    float* __restrict__ pm_y) {
  int t = threadIdx.x;
  int node = blockIdx.x * 16 + (t >> 4);
  int f = t & 15;
  if (node >= Nn) return;
  int b = row_start[node], e2 = row_start[node + 1];
  float acc0 = 0.f, acc1 = 0.f;
  int i = b;
  for (; i + 2 <= e2; i += 2) {
    int j0 = perm_pm[i];
    int j1 = perm_pm[i + 1];
    float v0 = pm_vals[j0], v1 = pm_vals[j1];
    int c0 = pm_cols[j0], c1 = pm_cols[j1];
    acc0 += v0 * feat_b[(size_t)c0 * 16 + f];
    acc1 += v1 * feat_b[(size_t)c1 * 16 + f];
  }
  if (i < e2) {
    int j = perm_pm[i];
    acc0 += pm_vals[j] * feat_b[(size_t)pm_cols[j] * 16 + f];
  }
  pm_y[(size_t)node * 16 + f] = acc0 + acc1;
}

// ---------------------------------------------------------------------------
// Fused per-node projections + ReLU(second half) + BN-stat partial reduction.
// ---------------------------------------------------------------------------
__global__ __launch_bounds__(256) void fuse_kernel(
    const float* __restrict__ feat_a, const float* __restrict__ deg,
    const float* __restrict__ z1, const float* __restrict__ z2,
    const float* __restrict__ z4, const float* __restrict__ pmy,
    const float* __restrict__ Wprev, const float* __restrict__ bprev,
    const float* __restrict__ Wdeg,  const float* __restrict__ bdeg,
    const float* __restrict__ Wrad,  const float* __restrict__ brad,
    const float* __restrict__ Wfuse, const float* __restrict__ bfuse,
    float* __restrict__ result, float* __restrict__ stats) {
  __shared__ float sWp[256], sWd[256], sWr[768], sWf[256], sB[16];
  int t = threadIdx.x;
  sWp[t] = Wprev[t];
  sWd[t] = Wdeg[t];
  sWf[t] = Wfuse[t];
  for (int i = t; i < 768; i += 256) sWr[i] = Wrad[i];
  if (t < 16)
    sB[t] = bprev[t] + bdeg[t] + brad[t] + brad[16 + t] + brad[32 + t] + bfuse[t];
  __syncthreads();

  int n = blockIdx.x * 256 + t;
  bool valid = n < Nn;

  float fa[16], a1[16], a2[16], a4[16], py[16];
  float dg = 0.f;
  if (valid) {
    const float4* p;
    p = (const float4*)(feat_a + (size_t)n * 16);
    ((float4*)fa)[0] = p[0]; ((float4*)fa)[1] = p[1];
    ((float4*)fa)[2] = p[2]; ((float4*)fa)[3] = p[3];
    p = (const float4*)(z1 + (size_t)n * 16);
    ((float4*)a1)[0] = p[0]; ((float4*)a1)[1] = p[1];
    ((float4*)a1)[2] = p[2]; ((float4*)a1)[3] = p[3];
    p = (const float4*)(z2 + (size_t)n * 16);
    ((float4*)a2)[0] = p[0]; ((float4*)a2)[1] = p[1];
    ((float4*)a2)[2] = p[2]; ((float4*)a2)[3] = p[3];
    p = (const float4*)(z4 + (size_t)n * 16);
    ((float4*)a4)[0] = p[0]; ((float4*)a4)[1] = p[1];
    ((float4*)a4)[2] = p[2]; ((float4*)a4)[3] = p[3];
    p = (const float4*)(pmy + (size_t)n * 16);
    ((float4*)py)[0] = p[0]; ((float4*)py)[1] = p[1];
    ((float4*)py)[2] = p[2]; ((float4*)py)[3] = p[3];
    dg = deg[n];
  } else {
#pragma unroll
    for (int i = 0; i < 16; i++) { fa[i] = a1[i] = a2[i] = a4[i] = py[i] = 0.f; }
  }

  float out[16];
#pragma unroll
  for (int o = 0; o < 16; o++) {
    float a = sB[o];
#pragma unroll
    for (int i = 0; i < 16; i++) {
      a += fa[i] * (sWp[i * 16 + o] + dg * sWd[i * 16 + o]);
      a += a1[i] * sWr[i * 16 + o];
      a += a2[i] * sWr[256 + i * 16 + o];
      a += a4[i] * sWr[512 + i * 16 + o];
      a += py[i] * sWf[i * 16 + o];
    }
    out[o] = (o >= 8) ? fmaxf(a, 0.f) : a;
  }

  if (valid) {
    float4* r = (float4*)(result + (size_t)n * 16);
    r[0] = ((float4*)out)[0]; r[1] = ((float4*)out)[1];
    r[2] = ((float4*)out)[2]; r[3] = ((float4*)out)[3];
  } else {
#pragma unroll
    for (int o = 0; o < 16; o++) out[o] = 0.f;
  }

#pragma unroll
  for (int o = 0; o < 16; o++) {
    float s = out[o];
    float q = out[o] * out[o];
#pragma unroll
    for (int m = 32; m >= 1; m >>= 1) {
      s += __shfl_xor(s, m, 64);
      q += __shfl_xor(q, m, 64);
    }
    if ((t & 63) == 0) {
      atomicAdd(&stats[o], s);
      atomicAdd(&stats[16 + o], q);
    }
  }
}

// ---------------------------------------------------------------------------
__global__ void bn_coeffs(float* __restrict__ stats,
                          const float* __restrict__ gamma,
                          const float* __restrict__ beta) {
  int t = threadIdx.x;
  if (t < 16) {
    float mean = stats[t] * (1.0f / Nn);
    float var  = stats[16 + t] * (1.0f / Nn) - mean * mean;
    float sc   = gamma[t] * rsqrtf(var + 1e-5f);
    stats[32 + t] = sc;
    stats[48 + t] = beta[t] - mean * sc;
  }
}

__global__ __launch_bounds__(256) void bn_apply(
    float* __restrict__ result, const float* __restrict__ stats) {
  int idx = blockIdx.x * 256 + threadIdx.x;          // over Nn*4
  if (idx >= Nn * 4) return;
  int c = (idx & 3) * 4;
  float4 r = ((const float4*)result)[idx];
  float4 o;
  o.x = r.x * stats[32 + c + 0] + stats[48 + c + 0];
  o.y = r.y * stats[32 + c + 1] + stats[48 + c + 1];
  o.z = r.z * stats[32 + c + 2] + stats[48 + c + 2];
  o.w = r.w * stats[32 + c + 3] + stats[48 + c + 3];
  ((float4*)result)[idx] = o;
}

// ---------------------------------------------------------------------------
extern "C" void kernel_launch(void* const* d_in, const int* in_sizes, int n_in,
                              void* d_out, int out_size, void* d_ws, size_t ws_size,
                              hipStream_t stream) {
  const float* feat_a  = (const float*)d_in[0];
  const float* feat_b  = (const float*)d_in[1];
  const float* deg     = (const float*)d_in[2];
  const float* pm_vals = (const float*)d_in[3];
  const float* W_prev  = (const float*)d_in[4];
  const float* b_prev  = (const float*)d_in[5];
  const float* W_deg   = (const float*)d_in[6];
  const float* b_deg   = (const float*)d_in[7];
  const float* W_rad   = (const float*)d_in[8];
  const float* b_rad   = (const float*)d_in[9];
  const float* W_fuse  = (const float*)d_in[10];
  const float* b_fuse  = (const float*)d_in[11];
  const float* bn_g    = (const float*)d_in[12];
  const float* bn_b    = (const float*)d_in[13];
  const int*   src     = (const int*)d_in[14];
  const int*   dst     = (const int*)d_in[15];
  const int*   pm_rows = (const int*)d_in[16];
  const int*   pm_cols = (const int*)d_in[17];

  float* ws = (float*)d_ws;
  float* z1   = ws;
  float* z2   = ws + (size_t)NF;
  float* z3   = ws + (size_t)2 * NF;
  float* z4   = ws + (size_t)3 * NF;
  float* pm_y = ws + (size_t)4 * NF;
  int* perm_src = (int*)(ws + (size_t)5 * NF);       // Ee
  int* perm_pm  = perm_src + Ee;                     // NNZn
  int* rs_e     = perm_pm + NNZn;                    // Nn+1
  int* cur_e    = rs_e + (Nn + 1);
  int* rs_p     = cur_e + (Nn + 1);
  int* cur_p    = rs_p + (Nn + 1);
  int* counts_e = cur_p + (Nn + 1);                  // Nn
  int* counts_p = counts_e + Nn;                     // Nn
  float* stats  = (float*)(counts_p + Nn);           // 64
  float* result = (float*)d_out;

  // zero counts_e, counts_p, stats (contiguous)
  hipMemsetAsync(counts_e, 0, ((size_t)2 * Nn + 64) * sizeof(int), stream);

  int idx_blocks = (Ee + NNZn + 255) / 256;          // 37500
  hist_kernel<<<idx_blocks, 256, 0, stream>>>(dst, pm_rows, counts_e, counts_p);
  scan2_kernel<<<2, 1024, 0, stream>>>(counts_e, counts_p, rs_e, cur_e, rs_p, cur_p);
  scatter_kernel<<<idx_blocks, 256, 0, stream>>>(src, dst, pm_rows, cur_e, cur_p,
                                                 perm_src, perm_pm);

  int gather_blocks = (Nn + 15) / 16;                // 6250
  hop_gather<<<gather_blocks, 256, 0, stream>>>(feat_a, z1, perm_src, rs_e);
  hop_gather<<<gather_blocks, 256, 0, stream>>>(z1, z2, perm_src, rs_e);
  hop_gather<<<gather_blocks, 256, 0, stream>>>(z2, z3, perm_src, rs_e);
  hop_gather<<<gather_blocks, 256, 0, stream>>>(z3, z4, perm_src, rs_e);

  pm_gather<<<gather_blocks, 256, 0, stream>>>(feat_b, pm_vals, pm_cols,
                                               perm_pm, rs_p, pm_y);

  int fuse_blocks = (Nn + 255) / 256;                // 391
  fuse_kernel<<<fuse_blocks, 256, 0, stream>>>(
      feat_a, deg, z1, z2, z4, pm_y,
      W_prev, b_prev, W_deg, b_deg, W_rad, b_rad, W_fuse, b_fuse,
      result, stats);

  bn_coeffs<<<1, 64, 0, stream>>>(stats, bn_g, bn_b);

  int bn_blocks = (Nn * 4 + 255) / 256;              // 1563
  bn_apply<<<bn_blocks, 256, 0, stream>>>(result, stats);
}

// Round 3
// 2643.878 us; speedup vs baseline: 1.6659x; 1.0176x over previous
//
#include <hip/hip_runtime.h>
#include <math.h>

#define Nn    100000
#define Ee    3200000
#define NNZn  6400000
#define NF    (Nn * 16)     // floats per node-feature buffer
#define K     1024          // row buckets
#define RPB   98            // rows per bucket = ceil(Nn/K)
#define CHUNK 16384         // items per binning block

// ---------------------------------------------------------------------------
// Count: per-block LDS histogram of key/RPB, one global atomic per bucket.
// ---------------------------------------------------------------------------
__global__ __launch_bounds__(256) void count_kernel(
    const int* __restrict__ keys, int n, int* __restrict__ tot) {
  __shared__ int h[K];
  int t = threadIdx.x;
  for (int i = t; i < K; i += 256) h[i] = 0;
  __syncthreads();
  int base = blockIdx.x * CHUNK;
  int end = min(base + CHUNK, n);
  for (int i = base + t; i < end; i += 256) atomicAdd(&h[keys[i] / RPB], 1);
  __syncthreads();
  for (int i = t; i < K; i += 256)
    if (h[i]) atomicAdd(&tot[i], h[i]);
}

// ---------------------------------------------------------------------------
// Exclusive scan of bucket totals -> bucket_start + cursor. 2 blocks x 1024.
// ---------------------------------------------------------------------------
__global__ __launch_bounds__(1024) void scan_kernel(
    const int* __restrict__ tot_e, const int* __restrict__ tot_p,
    int* __restrict__ bs_e, int* __restrict__ cur_e,
    int* __restrict__ bs_p, int* __restrict__ cur_p) {
  const int* tot = (blockIdx.x == 0) ? tot_e : tot_p;
  int* bs  = (blockIdx.x == 0) ? bs_e  : bs_p;
  int* cur = (blockIdx.x == 0) ? cur_e : cur_p;
  __shared__ int s[K];
  int t = threadIdx.x;
  s[t] = tot[t];
  __syncthreads();
  for (int off = 1; off < K; off <<= 1) {
    int v = (t >= off) ? s[t - off] : 0;
    __syncthreads();
    s[t] += v;
    __syncthreads();
  }
  int excl = t ? s[t - 1] : 0;
  bs[t] = excl;
  cur[t] = excl;
  if (t == K - 1) bs[K] = s[K - 1];
}

// ---------------------------------------------------------------------------
// Bin edges: binned_e[pos] = (local_row<<17) | src.  Runs of ~16 per bucket.
// ---------------------------------------------------------------------------
__global__ __launch_bounds__(256) void bin_edges(
    const int* __restrict__ dst, const int* __restrict__ src,
    int* __restrict__ cur, int* __restrict__ binned) {
  __shared__ int h[K];
  int t = threadIdx.x;
  for (int i = t; i < K; i += 256) h[i] = 0;
  __syncthreads();
  int base = blockIdx.x * CHUNK;
  int end = min(base + CHUNK, Ee);
  for (int i = base + t; i < end; i += 256) atomicAdd(&h[dst[i] / RPB], 1);
  __syncthreads();
  for (int k = t; k < K; k += 256) {
    int c = h[k];
    h[k] = c ? atomicAdd(&cur[k], c) : 0;
  }
  __syncthreads();
  for (int i = base + t; i < end; i += 256) {
    int d = dst[i];
    int k = d / RPB;
    int lr = d - k * RPB;
    int pos = atomicAdd(&h[k], 1);
    binned[pos] = (lr << 17) | src[i];
  }
}

// ---------------------------------------------------------------------------
// Bin pm: bp[pos] = { (local_row<<23)|col , bits(val) }
// ---------------------------------------------------------------------------
__global__ __launch_bounds__(256) void bin_pm(
    const int* __restrict__ rows, const int* __restrict__ cols,
    const float* __restrict__ vals,
    int* __restrict__ cur, int2* __restrict__ bp) {
  __shared__ int h[K];
  int t = threadIdx.x;
  for (int i = t; i < K; i += 256) h[i] = 0;
  __syncthreads();
  int base = blockIdx.x * CHUNK;
  int end = min(base + CHUNK, NNZn);
  for (int i = base + t; i < end; i += 256) atomicAdd(&h[rows[i] / RPB], 1);
  __syncthreads();
  for (int k = t; k < K; k += 256) {
    int c = h[k];
    h[k] = c ? atomicAdd(&cur[k], c) : 0;
  }
  __syncthreads();
  for (int i = base + t; i < end; i += 256) {
    int r = rows[i];
    int k = r / RPB;
    int lr = r - k * RPB;
    int pos = atomicAdd(&h[k], 1);
    bp[pos] = make_int2((lr << 23) | cols[i], __float_as_int(vals[i]));
  }
}

// ---------------------------------------------------------------------------
// Hop over one bucket: LDS row accumulators, streaming item reads.
// 16 item-groups x 16 features per 256-thread block.
// ---------------------------------------------------------------------------
__global__ __launch_bounds__(256) void hop_bucket(
    const float* __restrict__ zin, float* __restrict__ zout,
    const int* __restrict__ binned, const int* __restrict__ bs) {
  __shared__ float acc[RPB * 16];
  int t = threadIdx.x;
  int b = blockIdx.x;
  for (int i = t; i < RPB * 16; i += 256) acc[i] = 0.f;
  __syncthreads();
  int s0 = bs[b], s1 = bs[b + 1];
  int g = t >> 4, f = t & 15;
  for (int i = s0 + g; i < s1; i += 16) {
    int p = binned[i];
    int src = p & 0x1FFFF;
    int lr = p >> 17;
    atomicAdd(&acc[lr * 16 + f], zin[(size_t)src * 16 + f]);
  }
  __syncthreads();
  int r0 = b * RPB;
  int nr = min(RPB, Nn - r0);
  if (nr > 0)
    for (int i = t; i < nr * 16; i += 256) zout[(size_t)r0 * 16 + i] = acc[i];
}

// ---------------------------------------------------------------------------
// pm over one bucket: same structure, val * feat_b[col] gathers.
// ---------------------------------------------------------------------------
__global__ __launch_bounds__(256) void pm_bucket(
    const float* __restrict__ feat_b, const int2* __restrict__ bp,
    const int* __restrict__ bs, float* __restrict__ pm_y) {
  __shared__ float acc[RPB * 16];
  int t = threadIdx.x;
  int b = blockIdx.x;
  for (int i = t; i < RPB * 16; i += 256) acc[i] = 0.f;
  __syncthreads();
  int s0 = bs[b], s1 = bs[b + 1];
  int g = t >> 4, f = t & 15;
  for (int i = s0 + g; i < s1; i += 16) {
    int2 e = bp[i];
    int col = e.x & 0x7FFFFF;
    int lr = e.x >> 23;
    float v = __int_as_float(e.y);
    atomicAdd(&acc[lr * 16 + f], v * feat_b[(size_t)col * 16 + f]);
  }
  __syncthreads();
  int r0 = b * RPB;
  int nr = min(RPB, Nn - r0);
  if (nr > 0)
    for (int i = t; i < nr * 16; i += 256) pm_y[(size_t)r0 * 16 + i] = acc[i];
}

// ---------------------------------------------------------------------------
// Fused per-node projections + ReLU(second half) + BN-stat partial reduction.
// ---------------------------------------------------------------------------
__global__ __launch_bounds__(256) void fuse_kernel(
    const float* __restrict__ feat_a, const float* __restrict__ deg,
    const float* __restrict__ z1, const float* __restrict__ z2,
    const float* __restrict__ z4, const float* __restrict__ pmy,
    const float* __restrict__ Wprev, const float* __restrict__ bprev,
    const float* __restrict__ Wdeg,  const float* __restrict__ bdeg,
    const float* __restrict__ Wrad,  const float* __restrict__ brad,
    const float* __restrict__ Wfuse, const float* __restrict__ bfuse,
    float* __restrict__ result, float* __restrict__ stats) {
  __shared__ float sWp[256], sWd[256], sWr[768], sWf[256], sB[16];
  int t = threadIdx.x;
  sWp[t] = Wprev[t];
  sWd[t] = Wdeg[t];
  sWf[t] = Wfuse[t];
  for (int i = t; i < 768; i += 256) sWr[i] = Wrad[i];
  if (t < 16)
    sB[t] = bprev[t] + bdeg[t] + brad[t] + brad[16 + t] + brad[32 + t] + bfuse[t];
  __syncthreads();

  int n = blockIdx.x * 256 + t;
  bool valid = n < Nn;

  float fa[16], a1[16], a2[16], a4[16], py[16];
  float dg = 0.f;
  if (valid) {
    const float4* p;
    p = (const float4*)(feat_a + (size_t)n * 16);
    ((float4*)fa)[0] = p[0]; ((float4*)fa)[1] = p[1];
    ((float4*)fa)[2] = p[2]; ((float4*)fa)[3] = p[3];
    p = (const float4*)(z1 + (size_t)n * 16);
    ((float4*)a1)[0] = p[0]; ((float4*)a1)[1] = p[1];
    ((float4*)a1)[2] = p[2]; ((float4*)a1)[3] = p[3];
    p = (const float4*)(z2 + (size_t)n * 16);
    ((float4*)a2)[0] = p[0]; ((float4*)a2)[1] = p[1];
    ((float4*)a2)[2] = p[2]; ((float4*)a2)[3] = p[3];
    p = (const float4*)(z4 + (size_t)n * 16);
    ((float4*)a4)[0] = p[0]; ((float4*)a4)[1] = p[1];
    ((float4*)a4)[2] = p[2]; ((float4*)a4)[3] = p[3];
    p = (const float4*)(pmy + (size_t)n * 16);
    ((float4*)py)[0] = p[0]; ((float4*)py)[1] = p[1];
    ((float4*)py)[2] = p[2]; ((float4*)py)[3] = p[3];
    dg = deg[n];
  } else {
#pragma unroll
    for (int i = 0; i < 16; i++) { fa[i] = a1[i] = a2[i] = a4[i] = py[i] = 0.f; }
  }

  float out[16];
#pragma unroll
  for (int o = 0; o < 16; o++) {
    float a = sB[o];
#pragma unroll
    for (int i = 0; i < 16; i++) {
      a += fa[i] * (sWp[i * 16 + o] + dg * sWd[i * 16 + o]);
      a += a1[i] * sWr[i * 16 + o];
      a += a2[i] * sWr[256 + i * 16 + o];
      a += a4[i] * sWr[512 + i * 16 + o];
      a += py[i] * sWf[i * 16 + o];
    }
    out[o] = (o >= 8) ? fmaxf(a, 0.f) : a;
  }

  if (valid) {
    float4* r = (float4*)(result + (size_t)n * 16);
    r[0] = ((float4*)out)[0]; r[1] = ((float4*)out)[1];
    r[2] = ((float4*)out)[2]; r[3] = ((float4*)out)[3];
  } else {
#pragma unroll
    for (int o = 0; o < 16; o++) out[o] = 0.f;
  }

#pragma unroll
  for (int o = 0; o < 16; o++) {
    float s = out[o];
    float q = out[o] * out[o];
#pragma unroll
    for (int m = 32; m >= 1; m >>= 1) {
      s += __shfl_xor(s, m, 64);
      q += __shfl_xor(q, m, 64);
    }
    if ((t & 63) == 0) {
      atomicAdd(&stats[o], s);
      atomicAdd(&stats[16 + o], q);
    }
  }
}

// ---------------------------------------------------------------------------
__global__ void bn_coeffs(float* __restrict__ stats,
                          const float* __restrict__ gamma,
                          const float* __restrict__ beta) {
  int t = threadIdx.x;
  if (t < 16) {
    float mean = stats[t] * (1.0f / Nn);
    float var  = stats[16 + t] * (1.0f / Nn) - mean * mean;
    float sc   = gamma[t] * rsqrtf(var + 1e-5f);
    stats[32 + t] = sc;
    stats[48 + t] = beta[t] - mean * sc;
  }
}

__global__ __launch_bounds__(256) void bn_apply(
    float* __restrict__ result, const float* __restrict__ stats) {
  int idx = blockIdx.x * 256 + threadIdx.x;          // over Nn*4
  if (idx >= Nn * 4) return;
  int c = (idx & 3) * 4;
  float4 r = ((const float4*)result)[idx];
  float4 o;
  o.x = r.x * stats[32 + c + 0] + stats[48 + c + 0];
  o.y = r.y * stats[32 + c + 1] + stats[48 + c + 1];
  o.z = r.z * stats[32 + c + 2] + stats[48 + c + 2];
  o.w = r.w * stats[32 + c + 3] + stats[48 + c + 3];
  ((float4*)result)[idx] = o;
}

// ---------------------------------------------------------------------------
extern "C" void kernel_launch(void* const* d_in, const int* in_sizes, int n_in,
                              void* d_out, int out_size, void* d_ws, size_t ws_size,
                              hipStream_t stream) {
  const float* feat_a  = (const float*)d_in[0];
  const float* feat_b  = (const float*)d_in[1];
  const float* deg     = (const float*)d_in[2];
  const float* pm_vals = (const float*)d_in[3];
  const float* W_prev  = (const float*)d_in[4];
  const float* b_prev  = (const float*)d_in[5];
  const float* W_deg   = (const float*)d_in[6];
  const float* b_deg   = (const float*)d_in[7];
  const float* W_rad   = (const float*)d_in[8];
  const float* b_rad   = (const float*)d_in[9];
  const float* W_fuse  = (const float*)d_in[10];
  const float* b_fuse  = (const float*)d_in[11];
  const float* bn_g    = (const float*)d_in[12];
  const float* bn_b    = (const float*)d_in[13];
  const int*   src     = (const int*)d_in[14];
  const int*   dst     = (const int*)d_in[15];
  const int*   pm_rows = (const int*)d_in[16];
  const int*   pm_cols = (const int*)d_in[17];

  float* ws = (float*)d_ws;
  int*  binned_e = (int*)ws;                              // Ee ints
  int2* bp       = (int2*)(ws + (size_t)Ee);              // NNZn int2
  float* pm_y    = ws + (size_t)Ee + 2 * (size_t)NNZn;    // NF floats
  int* tab   = (int*)(pm_y + NF);
  int* tot_e = tab;               // K
  int* tot_p = tab + K;           // K
  int* bs_e  = tab + 2 * K;       // K+1
  int* cur_e = tab + 3 * K + 1;   // K
  int* bs_p  = tab + 4 * K + 1;   // K+1
  int* cur_p = tab + 5 * K + 2;   // K
  float* stats = (float*)(tab + 6 * K + 2);  // 64
  // z buffers alias the bp region (dead after pm_bucket): 4*NF <= 2*NNZn
  float* z1 = (float*)bp;
  float* z2 = z1 + (size_t)NF;
  float* z3 = z2 + (size_t)NF;
  float* z4 = z3 + (size_t)NF;
  float* result = (float*)d_out;

  // zero bucket totals + stats (bs/cur written by scan)
  hipMemsetAsync(tab, 0, (size_t)(6 * K + 2 + 64) * sizeof(int), stream);

  int cb_e = (Ee + CHUNK - 1) / CHUNK;     // 196
  int cb_p = (NNZn + CHUNK - 1) / CHUNK;   // 391
  count_kernel<<<cb_e, 256, 0, stream>>>(dst, Ee, tot_e);
  count_kernel<<<cb_p, 256, 0, stream>>>(pm_rows, NNZn, tot_p);
  scan_kernel<<<2, 1024, 0, stream>>>(tot_e, tot_p, bs_e, cur_e, bs_p, cur_p);
  bin_edges<<<cb_e, 256, 0, stream>>>(dst, src, cur_e, binned_e);
  bin_pm<<<cb_p, 256, 0, stream>>>(pm_rows, pm_cols, pm_vals, cur_p, bp);

  // pm first: consumes bp, freeing it for z1..z4
  pm_bucket<<<K, 256, 0, stream>>>(feat_b, bp, bs_p, pm_y);

  hop_bucket<<<K, 256, 0, stream>>>(feat_a, z1, binned_e, bs_e);
  hop_bucket<<<K, 256, 0, stream>>>(z1, z2, binned_e, bs_e);
  hop_bucket<<<K, 256, 0, stream>>>(z2, z3, binned_e, bs_e);
  hop_bucket<<<K, 256, 0, stream>>>(z3, z4, binned_e, bs_e);

  int fuse_blocks = (Nn + 255) / 256;
  fuse_kernel<<<fuse_blocks, 256, 0, stream>>>(
      feat_a, deg, z1, z2, z4, pm_y,
      W_prev, b_prev, W_deg, b_deg, W_rad, b_rad, W_fuse, b_fuse,
      result, stats);

  bn_coeffs<<<1, 64, 0, stream>>>(stats, bn_g, bn_b);

  int bn_blocks = (Nn * 4 + 255) / 256;
  bn_apply<<<bn_blocks, 256, 0, stream>>>(result, stats);
}

// Round 4
// 2551.073 us; speedup vs baseline: 1.7265x; 1.0364x over previous
//
#include <hip/hip_runtime.h>
#include <math.h>

#define Nn    100000
#define Ee    3200000
#define NNZn  6400000
#define NF    (Nn * 16)     // floats per node-feature buffer
#define K     1024          // row buckets
#define RPB   98            // rows per bucket = ceil(Nn/K)
#define CHUNK 16384         // items per binning block

// ---------------------------------------------------------------------------
// Count: per-block LDS histogram of key/RPB, one global atomic per bucket.
// ---------------------------------------------------------------------------
__global__ __launch_bounds__(256) void count_kernel(
    const int* __restrict__ keys, int n, int* __restrict__ tot) {
  __shared__ int h[K];
  int t = threadIdx.x;
  for (int i = t; i < K; i += 256) h[i] = 0;
  __syncthreads();
  int base = blockIdx.x * CHUNK;
  int end = min(base + CHUNK, n);
  for (int i = base + t; i < end; i += 256) atomicAdd(&h[keys[i] / RPB], 1);
  __syncthreads();
  for (int i = t; i < K; i += 256)
    if (h[i]) atomicAdd(&tot[i], h[i]);
}

// ---------------------------------------------------------------------------
// Exclusive scan of bucket totals -> bucket_start + cursor. 2 blocks x 1024.
// ---------------------------------------------------------------------------
__global__ __launch_bounds__(1024) void scan_kernel(
    const int* __restrict__ tot_e, const int* __restrict__ tot_p,
    int* __restrict__ bs_e, int* __restrict__ cur_e,
    int* __restrict__ bs_p, int* __restrict__ cur_p) {
  const int* tot = (blockIdx.x == 0) ? tot_e : tot_p;
  int* bs  = (blockIdx.x == 0) ? bs_e  : bs_p;
  int* cur = (blockIdx.x == 0) ? cur_e : cur_p;
  __shared__ int s[K];
  int t = threadIdx.x;
  s[t] = tot[t];
  __syncthreads();
  for (int off = 1; off < K; off <<= 1) {
    int v = (t >= off) ? s[t - off] : 0;
    __syncthreads();
    s[t] += v;
    __syncthreads();
  }
  int excl = t ? s[t - 1] : 0;
  bs[t] = excl;
  cur[t] = excl;
  if (t == K - 1) bs[K] = s[K - 1];
}

// ---------------------------------------------------------------------------
// Bin edges: binned_e[pos] = (local_row<<17) | src.  Runs of ~16 per bucket.
// ---------------------------------------------------------------------------
__global__ __launch_bounds__(256) void bin_edges(
    const int* __restrict__ dst, const int* __restrict__ src,
    int* __restrict__ cur, int* __restrict__ binned) {
  __shared__ int h[K];
  int t = threadIdx.x;
  for (int i = t; i < K; i += 256) h[i] = 0;
  __syncthreads();
  int base = blockIdx.x * CHUNK;
  int end = min(base + CHUNK, Ee);
  for (int i = base + t; i < end; i += 256) atomicAdd(&h[dst[i] / RPB], 1);
  __syncthreads();
  for (int k = t; k < K; k += 256) {
    int c = h[k];
    h[k] = c ? atomicAdd(&cur[k], c) : 0;
  }
  __syncthreads();
  for (int i = base + t; i < end; i += 256) {
    int d = dst[i];
    int k = d / RPB;
    int lr = d - k * RPB;
    int pos = atomicAdd(&h[k], 1);
    binned[pos] = (lr << 17) | src[i];
  }
}

// ---------------------------------------------------------------------------
// Bin pm: bp[pos] = { (local_row<<23)|col , bits(val) }
// ---------------------------------------------------------------------------
__global__ __launch_bounds__(256) void bin_pm(
    const int* __restrict__ rows, const int* __restrict__ cols,
    const float* __restrict__ vals,
    int* __restrict__ cur, int2* __restrict__ bp) {
  __shared__ int h[K];
  int t = threadIdx.x;
  for (int i = t; i < K; i += 256) h[i] = 0;
  __syncthreads();
  int base = blockIdx.x * CHUNK;
  int end = min(base + CHUNK, NNZn);
  for (int i = base + t; i < end; i += 256) atomicAdd(&h[rows[i] / RPB], 1);
  __syncthreads();
  for (int k = t; k < K; k += 256) {
    int c = h[k];
    h[k] = c ? atomicAdd(&cur[k], c) : 0;
  }
  __syncthreads();
  for (int i = base + t; i < end; i += 256) {
    int r = rows[i];
    int k = r / RPB;
    int lr = r - k * RPB;
    int pos = atomicAdd(&h[k], 1);
    bp[pos] = make_int2((lr << 23) | cols[i], __float_as_int(vals[i]));
  }
}

// ---------------------------------------------------------------------------
// Hop over one bucket: LDS row accumulators (stride 17 to break bank alias),
// 64 item-groups x 16 features per 1024-thread block, unroll x4 for MLP.
// ---------------------------------------------------------------------------
__global__ __launch_bounds__(1024) void hop_bucket(
    const float* __restrict__ zin, float* __restrict__ zout,
    const int* __restrict__ binned, const int* __restrict__ bs) {
  __shared__ float acc[RPB * 17];
  int t = threadIdx.x;
  int b = blockIdx.x;
  for (int i = t; i < RPB * 17; i += 1024) acc[i] = 0.f;
  __syncthreads();
  int s0 = bs[b], s1 = bs[b + 1];
  int g = t >> 4, f = t & 15;
  int i = s0 + g;
  for (; i + 192 < s1; i += 256) {
    int p0 = binned[i];
    int p1 = binned[i + 64];
    int p2 = binned[i + 128];
    int p3 = binned[i + 192];
    float x0 = zin[(size_t)(p0 & 0x1FFFF) * 16 + f];
    float x1 = zin[(size_t)(p1 & 0x1FFFF) * 16 + f];
    float x2 = zin[(size_t)(p2 & 0x1FFFF) * 16 + f];
    float x3 = zin[(size_t)(p3 & 0x1FFFF) * 16 + f];
    atomicAdd(&acc[(p0 >> 17) * 17 + f], x0);
    atomicAdd(&acc[(p1 >> 17) * 17 + f], x1);
    atomicAdd(&acc[(p2 >> 17) * 17 + f], x2);
    atomicAdd(&acc[(p3 >> 17) * 17 + f], x3);
  }
  for (; i < s1; i += 64) {
    int p = binned[i];
    atomicAdd(&acc[(p >> 17) * 17 + f], zin[(size_t)(p & 0x1FFFF) * 16 + f]);
  }
  __syncthreads();
  int r0 = b * RPB;
  int nr = min(RPB, Nn - r0);
  if (nr > 0)
    for (int j = t; j < nr * 16; j += 1024)
      zout[(size_t)r0 * 16 + j] = acc[(j >> 4) * 17 + (j & 15)];
}

// ---------------------------------------------------------------------------
// pm over one bucket: same structure, val * feat_b[col] gathers.
// ---------------------------------------------------------------------------
__global__ __launch_bounds__(1024) void pm_bucket(
    const float* __restrict__ feat_b, const int2* __restrict__ bp,
    const int* __restrict__ bs, float* __restrict__ pm_y) {
  __shared__ float acc[RPB * 17];
  int t = threadIdx.x;
  int b = blockIdx.x;
  for (int i = t; i < RPB * 17; i += 1024) acc[i] = 0.f;
  __syncthreads();
  int s0 = bs[b], s1 = bs[b + 1];
  int g = t >> 4, f = t & 15;
  int i = s0 + g;
  for (; i + 192 < s1; i += 256) {
    int2 e0 = bp[i];
    int2 e1 = bp[i + 64];
    int2 e2 = bp[i + 128];
    int2 e3 = bp[i + 192];
    float x0 = feat_b[(size_t)(e0.x & 0x7FFFFF) * 16 + f];
    float x1 = feat_b[(size_t)(e1.x & 0x7FFFFF) * 16 + f];
    float x2 = feat_b[(size_t)(e2.x & 0x7FFFFF) * 16 + f];
    float x3 = feat_b[(size_t)(e3.x & 0x7FFFFF) * 16 + f];
    atomicAdd(&acc[(e0.x >> 23) * 17 + f], __int_as_float(e0.y) * x0);
    atomicAdd(&acc[(e1.x >> 23) * 17 + f], __int_as_float(e1.y) * x1);
    atomicAdd(&acc[(e2.x >> 23) * 17 + f], __int_as_float(e2.y) * x2);
    atomicAdd(&acc[(e3.x >> 23) * 17 + f], __int_as_float(e3.y) * x3);
  }
  for (; i < s1; i += 64) {
    int2 e = bp[i];
    atomicAdd(&acc[(e.x >> 23) * 17 + f],
              __int_as_float(e.y) * feat_b[(size_t)(e.x & 0x7FFFFF) * 16 + f]);
  }
  __syncthreads();
  int r0 = b * RPB;
  int nr = min(RPB, Nn - r0);
  if (nr > 0)
    for (int j = t; j < nr * 16; j += 1024)
      pm_y[(size_t)r0 * 16 + j] = acc[(j >> 4) * 17 + (j & 15)];
}

// ---------------------------------------------------------------------------
// Fused per-node projections + ReLU(second half) + BN-stat partial reduction.
// ---------------------------------------------------------------------------
__global__ __launch_bounds__(256) void fuse_kernel(
    const float* __restrict__ feat_a, const float* __restrict__ deg,
    const float* __restrict__ z1, const float* __restrict__ z2,
    const float* __restrict__ z4, const float* __restrict__ pmy,
    const float* __restrict__ Wprev, const float* __restrict__ bprev,
    const float* __restrict__ Wdeg,  const float* __restrict__ bdeg,
    const float* __restrict__ Wrad,  const float* __restrict__ brad,
    const float* __restrict__ Wfuse, const float* __restrict__ bfuse,
    float* __restrict__ result, float* __restrict__ stats) {
  __shared__ float sWp[256], sWd[256], sWr[768], sWf[256], sB[16];
  int t = threadIdx.x;
  sWp[t] = Wprev[t];
  sWd[t] = Wdeg[t];
  sWf[t] = Wfuse[t];
  for (int i = t; i < 768; i += 256) sWr[i] = Wrad[i];
  if (t < 16)
    sB[t] = bprev[t] + bdeg[t] + brad[t] + brad[16 + t] + brad[32 + t] + bfuse[t];
  __syncthreads();

  int n = blockIdx.x * 256 + t;
  bool valid = n < Nn;

  float fa[16], a1[16], a2[16], a4[16], py[16];
  float dg = 0.f;
  if (valid) {
    const float4* p;
    p = (const float4*)(feat_a + (size_t)n * 16);
    ((float4*)fa)[0] = p[0]; ((float4*)fa)[1] = p[1];
    ((float4*)fa)[2] = p[2]; ((float4*)fa)[3] = p[3];
    p = (const float4*)(z1 + (size_t)n * 16);
    ((float4*)a1)[0] = p[0]; ((float4*)a1)[1] = p[1];
    ((float4*)a1)[2] = p[2]; ((float4*)a1)[3] = p[3];
    p = (const float4*)(z2 + (size_t)n * 16);
    ((float4*)a2)[0] = p[0]; ((float4*)a2)[1] = p[1];
    ((float4*)a2)[2] = p[2]; ((float4*)a2)[3] = p[3];
    p = (const float4*)(z4 + (size_t)n * 16);
    ((float4*)a4)[0] = p[0]; ((float4*)a4)[1] = p[1];
    ((float4*)a4)[2] = p[2]; ((float4*)a4)[3] = p[3];
    p = (const float4*)(pmy + (size_t)n * 16);
    ((float4*)py)[0] = p[0]; ((float4*)py)[1] = p[1];
    ((float4*)py)[2] = p[2]; ((float4*)py)[3] = p[3];
    dg = deg[n];
  } else {
#pragma unroll
    for (int i = 0; i < 16; i++) { fa[i] = a1[i] = a2[i] = a4[i] = py[i] = 0.f; }
  }

  float out[16];
#pragma unroll
  for (int o = 0; o < 16; o++) {
    float a = sB[o];
#pragma unroll
    for (int i = 0; i < 16; i++) {
      a += fa[i] * (sWp[i * 16 + o] + dg * sWd[i * 16 + o]);
      a += a1[i] * sWr[i * 16 + o];
      a += a2[i] * sWr[256 + i * 16 + o];
      a += a4[i] * sWr[512 + i * 16 + o];
      a += py[i] * sWf[i * 16 + o];
    }
    out[o] = (o >= 8) ? fmaxf(a, 0.f) : a;
  }

  if (valid) {
    float4* r = (float4*)(result + (size_t)n * 16);
    r[0] = ((float4*)out)[0]; r[1] = ((float4*)out)[1];
    r[2] = ((float4*)out)[2]; r[3] = ((float4*)out)[3];
  } else {
#pragma unroll
    for (int o = 0; o < 16; o++) out[o] = 0.f;
  }

#pragma unroll
  for (int o = 0; o < 16; o++) {
    float s = out[o];
    float q = out[o] * out[o];
#pragma unroll
    for (int m = 32; m >= 1; m >>= 1) {
      s += __shfl_xor(s, m, 64);
      q += __shfl_xor(q, m, 64);
    }
    if ((t & 63) == 0) {
      atomicAdd(&stats[o], s);
      atomicAdd(&stats[16 + o], q);
    }
  }
}

// ---------------------------------------------------------------------------
__global__ void bn_coeffs(float* __restrict__ stats,
                          const float* __restrict__ gamma,
                          const float* __restrict__ beta) {
  int t = threadIdx.x;
  if (t < 16) {
    float mean = stats[t] * (1.0f / Nn);
    float var  = stats[16 + t] * (1.0f / Nn) - mean * mean;
    float sc   = gamma[t] * rsqrtf(var + 1e-5f);
    stats[32 + t] = sc;
    stats[48 + t] = beta[t] - mean * sc;
  }
}

__global__ __launch_bounds__(256) void bn_apply(
    float* __restrict__ result, const float* __restrict__ stats) {
  int idx = blockIdx.x * 256 + threadIdx.x;          // over Nn*4
  if (idx >= Nn * 4) return;
  int c = (idx & 3) * 4;
  float4 r = ((const float4*)result)[idx];
  float4 o;
  o.x = r.x * stats[32 + c + 0] + stats[48 + c + 0];
  o.y = r.y * stats[32 + c + 1] + stats[48 + c + 1];
  o.z = r.z * stats[32 + c + 2] + stats[48 + c + 2];
  o.w = r.w * stats[32 + c + 3] + stats[48 + c + 3];
  ((float4*)result)[idx] = o;
}

// ---------------------------------------------------------------------------
extern "C" void kernel_launch(void* const* d_in, const int* in_sizes, int n_in,
                              void* d_out, int out_size, void* d_ws, size_t ws_size,
                              hipStream_t stream) {
  const float* feat_a  = (const float*)d_in[0];
  const float* feat_b  = (const float*)d_in[1];
  const float* deg     = (const float*)d_in[2];
  const float* pm_vals = (const float*)d_in[3];
  const float* W_prev  = (const float*)d_in[4];
  const float* b_prev  = (const float*)d_in[5];
  const float* W_deg   = (const float*)d_in[6];
  const float* b_deg   = (const float*)d_in[7];
  const float* W_rad   = (const float*)d_in[8];
  const float* b_rad   = (const float*)d_in[9];
  const float* W_fuse  = (const float*)d_in[10];
  const float* b_fuse  = (const float*)d_in[11];
  const float* bn_g    = (const float*)d_in[12];
  const float* bn_b    = (const float*)d_in[13];
  const int*   src     = (const int*)d_in[14];
  const int*   dst     = (const int*)d_in[15];
  const int*   pm_rows = (const int*)d_in[16];
  const int*   pm_cols = (const int*)d_in[17];

  float* ws = (float*)d_ws;
  int*  binned_e = (int*)ws;                              // Ee ints
  int2* bp       = (int2*)(ws + (size_t)Ee);              // NNZn int2
  float* pm_y    = ws + (size_t)Ee + 2 * (size_t)NNZn;    // NF floats
  int* tab   = (int*)(pm_y + NF);
  int* tot_e = tab;               // K
  int* tot_p = tab + K;           // K
  int* bs_e  = tab + 2 * K;       // K+1
  int* cur_e = tab + 3 * K + 1;   // K
  int* bs_p  = tab + 4 * K + 1;   // K+1
  int* cur_p = tab + 5 * K + 2;   // K
  float* stats = (float*)(tab + 6 * K + 2);  // 64
  // z buffers alias the bp region (dead after pm_bucket): 4*NF <= 2*NNZn
  float* z1 = (float*)bp;
  float* z2 = z1 + (size_t)NF;
  float* z3 = z2 + (size_t)NF;
  float* z4 = z3 + (size_t)NF;
  float* result = (float*)d_out;

  // zero bucket totals + stats (bs/cur written by scan)
  hipMemsetAsync(tab, 0, (size_t)(6 * K + 2 + 64) * sizeof(int), stream);

  int cb_e = (Ee + CHUNK - 1) / CHUNK;     // 196
  int cb_p = (NNZn + CHUNK - 1) / CHUNK;   // 391
  count_kernel<<<cb_e, 256, 0, stream>>>(dst, Ee, tot_e);
  count_kernel<<<cb_p, 256, 0, stream>>>(pm_rows, NNZn, tot_p);
  scan_kernel<<<2, 1024, 0, stream>>>(tot_e, tot_p, bs_e, cur_e, bs_p, cur_p);
  bin_edges<<<cb_e, 256, 0, stream>>>(dst, src, cur_e, binned_e);
  bin_pm<<<cb_p, 256, 0, stream>>>(pm_rows, pm_cols, pm_vals, cur_p, bp);

  // pm first: consumes bp, freeing it for z1..z4
  pm_bucket<<<K, 1024, 0, stream>>>(feat_b, bp, bs_p, pm_y);

  hop_bucket<<<K, 1024, 0, stream>>>(feat_a, z1, binned_e, bs_e);
  hop_bucket<<<K, 1024, 0, stream>>>(z1, z2, binned_e, bs_e);
  hop_bucket<<<K, 1024, 0, stream>>>(z2, z3, binned_e, bs_e);
  hop_bucket<<<K, 1024, 0, stream>>>(z3, z4, binned_e, bs_e);

  int fuse_blocks = (Nn + 255) / 256;
  fuse_kernel<<<fuse_blocks, 256, 0, stream>>>(
      feat_a, deg, z1, z2, z4, pm_y,
      W_prev, b_prev, W_deg, b_deg, W_rad, b_rad, W_fuse, b_fuse,
      result, stats);

  bn_coeffs<<<1, 64, 0, stream>>>(stats, bn_g, bn_b);

  int bn_blocks = (Nn * 4 + 255) / 256;
  bn_apply<<<bn_blocks, 256, 0, stream>>>(result, stats);
}